// Round 1
// baseline (108.047 us; speedup 1.0000x reference)
//
#include <hip/hip_runtime.h>
#include <hip/hip_bf16.h>

namespace {
constexpr int V_     = 6;
constexpr int DIM_   = 384;
constexpr int PH_    = 37;
constexpr int PW_    = 37;
constexpr int PP_    = PH_ * PW_;      // 1369
constexpr int NBV_   = 12;             // B*V
constexpr float FPATCH_ = 14.0f;
constexpr float FIMG_   = 518.0f;      // H == W == 37*14
}

// ---------------------------------------------------------------------------
// Kernel 1: precompute P = K @ E[:3,:] (12 x 3 x 4) and extrinsic row 2 (12 x 4)
// ---------------------------------------------------------------------------
__global__ void precompute_P(const float* __restrict__ intr,
                             const float* __restrict__ extr,
                             float* __restrict__ Pmat,   // [12][12]
                             float* __restrict__ R2) {   // [12][4]
    int t = threadIdx.x;
    if (t < NBV_ * 12) {
        int m = t / 12, e = t % 12, i = e >> 2, k = e & 3;
        const float* K = intr + m * 9;
        const float* E = extr + m * 16;
        Pmat[t] = K[i*3+0]*E[0*4+k] + K[i*3+1]*E[1*4+k] + K[i*3+2]*E[2*4+k];
    } else if (t < NBV_ * 12 + NBV_ * 4) {
        int u = t - NBV_ * 12;
        int m = u >> 2, k = u & 3;
        R2[u] = extr[m*16 + 8 + k];
    }
}

// ---------------------------------------------------------------------------
// Kernel 2: tiled transpose dino (12, 384, 1369) -> tdino (12, 1369, 384)
// ---------------------------------------------------------------------------
__global__ void transpose_dino(const float* __restrict__ dino,
                               float* __restrict__ tdino) {
    __shared__ float tile[32][33];
    int bv = blockIdx.z;
    int p0 = blockIdx.x * 32;   // patch (1369) tile origin
    int d0 = blockIdx.y * 32;   // dim (384) tile origin
    const float* in  = dino  + (size_t)bv * DIM_ * PP_;
    float*       out = tdino + (size_t)bv * PP_  * DIM_;
    int tx = threadIdx.x, ty = threadIdx.y;   // block (32, 8)
#pragma unroll
    for (int k = 0; k < 4; k++) {
        int d = d0 + ty + k * 8;   // 384 % 32 == 0, always in-bounds
        int p = p0 + tx;
        if (p < PP_) tile[ty + k * 8][tx] = in[(size_t)d * PP_ + p];
    }
    __syncthreads();
#pragma unroll
    for (int k = 0; k < 4; k++) {
        int p = p0 + ty + k * 8;
        int d = d0 + tx;
        if (p < PP_) out[(size_t)p * DIM_ + d] = tile[tx][ty + k * 8];
    }
}

// ---------------------------------------------------------------------------
// Per-point projection -> patch index (bv*1369 + vp*37 + up), or -1
// ---------------------------------------------------------------------------
__device__ __forceinline__ int project_point(float x, float y, float z, int b,
                                             const float* __restrict__ Pmat,
                                             const float* __restrict__ R2) {
    int sel = -1;
    int selp = 0;
#pragma unroll
    for (int v = 0; v < V_; v++) {
        int m = b * V_ + v;
        const float* P = Pmat + m * 12;
        const float* r = R2 + m * 4;
        float pc0   = P[0]*x + P[1]*y + P[2]*z  + P[3];
        float pc1   = P[4]*x + P[5]*y + P[6]*z  + P[7];
        float w     = P[8]*x + P[9]*y + P[10]*z + P[11];
        float depth = r[0]*x + r[1]*y + r[2]*z  + r[3];
        float u  = pc0 / w;
        float vc = pc1 / w;
        bool valid = (depth > 0.1f) && (u >= 0.0f) && (u < FIMG_)
                                    && (vc >= 0.0f) && (vc < FIMG_);
        if (valid) {
            int up = (int)floorf(u  / FPATCH_);
            int vp = (int)floorf(vc / FPATCH_);
            up = min(max(up, 0), PW_ - 1);
            vp = min(max(vp, 0), PH_ - 1);
            sel  = v;                       // keep overwriting -> max valid v
            selp = m * PP_ + vp * PW_ + up;
        }
    }
    return (sel >= 0) ? selp : -1;
}

// ---------------------------------------------------------------------------
// Kernel 3: one thread per point -> patch offset (or -1)
// ---------------------------------------------------------------------------
__global__ void project_kernel(const float* __restrict__ pts,
                               const int* __restrict__ bi,
                               const float* __restrict__ Pmat,
                               const float* __restrict__ R2,
                               int* __restrict__ offs, int N) {
    int n = blockIdx.x * blockDim.x + threadIdx.x;
    if (n >= N) return;
    float x = pts[n*3+0], y = pts[n*3+1], z = pts[n*3+2];
    offs[n] = project_point(x, y, z, bi[n], Pmat, R2);
}

// ---------------------------------------------------------------------------
// Kernel 4: coalesced gather+write. One thread per (point, float4 chunk).
// ---------------------------------------------------------------------------
__global__ void gather_kernel(const float* __restrict__ tdino,
                              const int* __restrict__ offs,
                              float* __restrict__ out, int N) {
    int gid = blockIdx.x * blockDim.x + threadIdx.x;
    int n = gid / 96;
    int c = gid - n * 96;
    if (n >= N) return;
    int patch = offs[n];
    float4 val;
    if (patch < 0) {
        val = make_float4(0.f, 0.f, 0.f, 0.f);
    } else {
        const float4* src =
            reinterpret_cast<const float4*>(tdino + (size_t)patch * DIM_);
        val = src[c];
    }
    reinterpret_cast<float4*>(out)[(size_t)n * 96 + c] = val;
}

// ---------------------------------------------------------------------------
// Fallback (ws too small): fully inline, strided gather from native dino.
// One thread per (point, float4 chunk); projection recomputed per thread.
// ---------------------------------------------------------------------------
__global__ void fallback_kernel(const float* __restrict__ pts,
                                const int* __restrict__ bi,
                                const float* __restrict__ intr,
                                const float* __restrict__ extr,
                                const float* __restrict__ dino,
                                float* __restrict__ out, int N) {
    int gid = blockIdx.x * blockDim.x + threadIdx.x;
    int n = gid / 96;
    int c = gid - n * 96;
    if (n >= N) return;
    float x = pts[n*3+0], y = pts[n*3+1], z = pts[n*3+2];
    int b = bi[n];
    // inline P computation (small, L1-cached tables)
    int sel = -1; int selp = 0;
    for (int v = 0; v < V_; v++) {
        int m = b * V_ + v;
        const float* K = intr + m * 9;
        const float* E = extr + m * 16;
        float P0[4], P1[4], P2[4];
#pragma unroll
        for (int k = 0; k < 4; k++) {
            P0[k] = K[0]*E[0*4+k] + K[1]*E[1*4+k] + K[2]*E[2*4+k];
            P1[k] = K[3]*E[0*4+k] + K[4]*E[1*4+k] + K[5]*E[2*4+k];
            P2[k] = K[6]*E[0*4+k] + K[7]*E[1*4+k] + K[8]*E[2*4+k];
        }
        float pc0   = P0[0]*x + P0[1]*y + P0[2]*z + P0[3];
        float pc1   = P1[0]*x + P1[1]*y + P1[2]*z + P1[3];
        float w     = P2[0]*x + P2[1]*y + P2[2]*z + P2[3];
        float depth = E[8]*x + E[9]*y + E[10]*z + E[11];
        float u  = pc0 / w;
        float vc = pc1 / w;
        bool valid = (depth > 0.1f) && (u >= 0.0f) && (u < FIMG_)
                                    && (vc >= 0.0f) && (vc < FIMG_);
        if (valid) {
            int up = (int)floorf(u  / FPATCH_);
            int vp = (int)floorf(vc / FPATCH_);
            up = min(max(up, 0), PW_ - 1);
            vp = min(max(vp, 0), PH_ - 1);
            sel = v;
            selp = m * PP_ + vp * PW_ + up;
        }
    }
    float4 val = make_float4(0.f, 0.f, 0.f, 0.f);
    if (sel >= 0) {
        // native layout: dino[(bv*384 + d)*1369 + p]
        int bvbase = (selp / PP_) * DIM_;      // bv*384
        int p      = selp % PP_;
        int d = c * 4;
        val.x = dino[(size_t)(bvbase + d + 0) * PP_ + p];
        val.y = dino[(size_t)(bvbase + d + 1) * PP_ + p];
        val.z = dino[(size_t)(bvbase + d + 2) * PP_ + p];
        val.w = dino[(size_t)(bvbase + d + 3) * PP_ + p];
    }
    reinterpret_cast<float4*>(out)[(size_t)n * 96 + c] = val;
}

extern "C" void kernel_launch(void* const* d_in, const int* in_sizes, int n_in,
                              void* d_out, int out_size, void* d_ws, size_t ws_size,
                              hipStream_t stream) {
    const float* pts  = (const float*)d_in[0];   // (N,3)
    // d_in[1] = imgs (unused)
    const float* intr = (const float*)d_in[2];   // (2,6,3,3)
    const float* extr = (const float*)d_in[3];   // (2,6,4,4)
    const float* dino = (const float*)d_in[4];   // (2,6,384,37,37)
    const int*   bi   = (const int*)d_in[5];     // (N,)
    float* out = (float*)d_out;

    const int N = in_sizes[5];                   // 250000

    // workspace layout (fast path):
    //   [0      .. 768)        : Pmat (144 f) + R2 (48 f)
    //   [1024   .. 1024+4N)    : offs (int[N])
    //   [1024+4N .. +25.2MB)   : tdino (12*1369*384 floats), 16B-aligned
    const size_t offs_off  = 1024;
    const size_t tdino_off = offs_off + (size_t)N * 4;
    const size_t tdino_bytes = (size_t)NBV_ * PP_ * DIM_ * 4;
    const size_t need = tdino_off + tdino_bytes;

    const int total = N * 96;
    const int gblocks = (total + 255) / 256;

    if (ws_size >= need) {
        float* Pmat  = (float*)d_ws;
        float* R2    = Pmat + NBV_ * 12;
        int*   offs  = (int*)((char*)d_ws + offs_off);
        float* tdino = (float*)((char*)d_ws + tdino_off);

        precompute_P<<<1, 192, 0, stream>>>(intr, extr, Pmat, R2);
        dim3 tb(32, 8);
        dim3 tg((PP_ + 31) / 32, DIM_ / 32, NBV_);
        transpose_dino<<<tg, tb, 0, stream>>>(dino, tdino);
        project_kernel<<<(N + 255) / 256, 256, 0, stream>>>(pts, bi, Pmat, R2, offs, N);
        gather_kernel<<<gblocks, 256, 0, stream>>>(tdino, offs, out, N);
    } else {
        fallback_kernel<<<gblocks, 256, 0, stream>>>(pts, bi, intr, extr, dino, out, N);
    }
}

// Round 3
// 87.576 us; speedup vs baseline: 1.2338x; 1.2338x over previous
//
#include <hip/hip_runtime.h>
#include <hip/hip_bf16.h>

typedef float f32x4 __attribute__((ext_vector_type(4)));

namespace {
constexpr int V_     = 6;
constexpr int DIM_   = 384;
constexpr int PH_    = 37;
constexpr int PW_    = 37;
constexpr int PP_    = PH_ * PW_;      // 1369
constexpr int NBV_   = 12;             // B*V
constexpr float FPATCH_ = 14.0f;
constexpr float FIMG_   = 518.0f;      // H == W == 37*14

constexpr int TPX_ = (PP_ + 31) / 32;  // 43 patch tiles
constexpr int TPY_ = DIM_ / 32;        // 12 dim tiles
constexpr int TPB_ = TPX_ * TPY_;      // 516 blocks per bv
constexpr int TP_TOTAL_ = TPB_ * NBV_; // 6192 transpose blocks
constexpr int PTSB_ = 16;              // points per gather block
}

// ---------------------------------------------------------------------------
// Kernel A: blocks [0, TP_TOTAL_) transpose dino (12,384,1369)->(12,1369,384);
//           block TP_TOTAL_ precomputes P = K @ E[:3,:] and extr row 2.
// ---------------------------------------------------------------------------
__global__ __launch_bounds__(256)
void prep_kernel(const float* __restrict__ dino,
                 float* __restrict__ tdino,
                 const float* __restrict__ intr,
                 const float* __restrict__ extr,
                 float* __restrict__ Pmat,   // [12][12]
                 float* __restrict__ R2) {   // [12][4]
    int blk = blockIdx.x;
    int tx = threadIdx.x, ty = threadIdx.y;          // (32, 8)

    if (blk >= TP_TOTAL_) {                          // precompute block
        int t = ty * 32 + tx;
        if (t < NBV_ * 12) {
            int m = t / 12, e = t % 12, i = e >> 2, k = e & 3;
            const float* K = intr + m * 9;
            const float* E = extr + m * 16;
            Pmat[t] = K[i*3+0]*E[0*4+k] + K[i*3+1]*E[1*4+k] + K[i*3+2]*E[2*4+k];
        } else if (t < NBV_ * 12 + NBV_ * 4) {
            int u = t - NBV_ * 12;
            int m = u >> 2, k = u & 3;
            R2[u] = extr[m*16 + 8 + k];
        }
        return;
    }

    __shared__ float tile[32][33];
    int bv  = blk / TPB_;
    int rem = blk % TPB_;
    int p0  = (rem % TPX_) * 32;                     // patch tile origin
    int d0  = (rem / TPX_) * 32;                     // dim tile origin
    const float* in  = dino  + (size_t)bv * DIM_ * PP_;
    float*       out = tdino + (size_t)bv * PP_  * DIM_;
#pragma unroll
    for (int k = 0; k < 4; k++) {
        int d = d0 + ty + k * 8;                     // always < 384
        int p = p0 + tx;
        if (p < PP_) tile[ty + k * 8][tx] = in[(size_t)d * PP_ + p];
    }
    __syncthreads();
#pragma unroll
    for (int k = 0; k < 4; k++) {
        int p = p0 + ty + k * 8;
        int d = d0 + tx;
        if (p < PP_) out[(size_t)p * DIM_ + d] = tile[tx][ty + k * 8];
    }
}

// ---------------------------------------------------------------------------
// Kernel B: fused project + gather. Block = 256 threads, PTSB_ points.
//   1) load Pmat/R2 into LDS
//   2) threads [0,PTSB_) project their point -> patch offset (or -1) in LDS
//   3) all threads stream PTSB_*96 f32x4 chunks to out (nontemporal)
// ---------------------------------------------------------------------------
__global__ __launch_bounds__(256)
void gather_fused(const float* __restrict__ pts,
                  const int* __restrict__ bi,
                  const float* __restrict__ Pmat,
                  const float* __restrict__ R2,
                  const float* __restrict__ tdino,
                  float* __restrict__ out, int N) {
    __shared__ float sP[NBV_ * 12];
    __shared__ float sR[NBV_ * 4];
    __shared__ int   soff[PTSB_];

    int t  = threadIdx.x;
    int n0 = blockIdx.x * PTSB_;

    if (t < NBV_ * 12)                 sP[t]             = Pmat[t];
    else if (t < NBV_ * 12 + NBV_ * 4) sR[t - NBV_ * 12] = R2[t - NBV_ * 12];
    __syncthreads();

    if (t < PTSB_) {
        int n = n0 + t;
        int result = -1;
        if (n < N) {
            float x = pts[n*3+0], y = pts[n*3+1], z = pts[n*3+2];
            int b = bi[n];
#pragma unroll
            for (int v = 0; v < V_; v++) {
                int m = b * V_ + v;
                const float* P = sP + m * 12;
                const float* r = sR + m * 4;
                float pc0   = P[0]*x + P[1]*y + P[2]*z  + P[3];
                float pc1   = P[4]*x + P[5]*y + P[6]*z  + P[7];
                float w     = P[8]*x + P[9]*y + P[10]*z + P[11];
                float depth = r[0]*x + r[1]*y + r[2]*z  + r[3];
                float u  = pc0 / w;
                float vc = pc1 / w;
                bool valid = (depth > 0.1f) && (u >= 0.0f) && (u < FIMG_)
                                            && (vc >= 0.0f) && (vc < FIMG_);
                if (valid) {
                    int up = (int)floorf(u  / FPATCH_);
                    int vp = (int)floorf(vc / FPATCH_);
                    up = min(max(up, 0), PW_ - 1);
                    vp = min(max(vp, 0), PH_ - 1);
                    result = m * PP_ + vp * PW_ + up;   // max valid v wins
                }
            }
        }
        soff[t] = result;
    }
    __syncthreads();

#pragma unroll
    for (int i = 0; i < (PTSB_ * 96) / 256; i++) {
        int idx = i * 256 + t;                        // 0 .. PTSB_*96
        int nl  = idx / 96;
        int c   = idx - nl * 96;
        int n   = n0 + nl;
        if (n >= N) break;
        int patch = soff[nl];
        f32x4 val;
        if (patch < 0) {
            val = (f32x4)(0.f);
        } else {
            val = reinterpret_cast<const f32x4*>(
                      tdino + (size_t)patch * DIM_)[c];
        }
        __builtin_nontemporal_store(
            val, reinterpret_cast<f32x4*>(out) + (size_t)n * 96 + c);
    }
}

// ---------------------------------------------------------------------------
// Fallback (ws too small): fully inline, strided gather from native dino.
// ---------------------------------------------------------------------------
__global__ void fallback_kernel(const float* __restrict__ pts,
                                const int* __restrict__ bi,
                                const float* __restrict__ intr,
                                const float* __restrict__ extr,
                                const float* __restrict__ dino,
                                float* __restrict__ out, int N) {
    int gid = blockIdx.x * blockDim.x + threadIdx.x;
    int n = gid / 96;
    int c = gid - n * 96;
    if (n >= N) return;
    float x = pts[n*3+0], y = pts[n*3+1], z = pts[n*3+2];
    int b = bi[n];
    int sel = -1; int selp = 0;
    for (int v = 0; v < V_; v++) {
        int m = b * V_ + v;
        const float* K = intr + m * 9;
        const float* E = extr + m * 16;
        float P0[4], P1[4], P2[4];
#pragma unroll
        for (int k = 0; k < 4; k++) {
            P0[k] = K[0]*E[0*4+k] + K[1]*E[1*4+k] + K[2]*E[2*4+k];
            P1[k] = K[3]*E[0*4+k] + K[4]*E[1*4+k] + K[5]*E[2*4+k];
            P2[k] = K[6]*E[0*4+k] + K[7]*E[1*4+k] + K[8]*E[2*4+k];
        }
        float pc0   = P0[0]*x + P0[1]*y + P0[2]*z + P0[3];
        float pc1   = P1[0]*x + P1[1]*y + P1[2]*z + P1[3];
        float w     = P2[0]*x + P2[1]*y + P2[2]*z + P2[3];
        float depth = E[8]*x + E[9]*y + E[10]*z + E[11];
        float u  = pc0 / w;
        float vc = pc1 / w;
        bool valid = (depth > 0.1f) && (u >= 0.0f) && (u < FIMG_)
                                    && (vc >= 0.0f) && (vc < FIMG_);
        if (valid) {
            int up = (int)floorf(u  / FPATCH_);
            int vp = (int)floorf(vc / FPATCH_);
            up = min(max(up, 0), PW_ - 1);
            vp = min(max(vp, 0), PH_ - 1);
            sel = v;
            selp = m * PP_ + vp * PW_ + up;
        }
    }
    float4 val = make_float4(0.f, 0.f, 0.f, 0.f);
    if (sel >= 0) {
        int bvbase = (selp / PP_) * DIM_;
        int p      = selp % PP_;
        int d = c * 4;
        val.x = dino[(size_t)(bvbase + d + 0) * PP_ + p];
        val.y = dino[(size_t)(bvbase + d + 1) * PP_ + p];
        val.z = dino[(size_t)(bvbase + d + 2) * PP_ + p];
        val.w = dino[(size_t)(bvbase + d + 3) * PP_ + p];
    }
    reinterpret_cast<float4*>(out)[(size_t)n * 96 + c] = val;
}

extern "C" void kernel_launch(void* const* d_in, const int* in_sizes, int n_in,
                              void* d_out, int out_size, void* d_ws, size_t ws_size,
                              hipStream_t stream) {
    const float* pts  = (const float*)d_in[0];   // (N,3)
    // d_in[1] = imgs (unused)
    const float* intr = (const float*)d_in[2];   // (2,6,3,3)
    const float* extr = (const float*)d_in[3];   // (2,6,4,4)
    const float* dino = (const float*)d_in[4];   // (2,6,384,37,37)
    const int*   bi   = (const int*)d_in[5];     // (N,)
    float* out = (float*)d_out;

    const int N = in_sizes[5];                   // 250000

    // workspace layout (fast path):
    //   [0    .. 768)      : Pmat (144 f) + R2 (48 f)
    //   [1024 .. +25.2MB)  : tdino (12*1369*384 floats), 16B-aligned
    const size_t tdino_off   = 1024;
    const size_t tdino_bytes = (size_t)NBV_ * PP_ * DIM_ * 4;
    const size_t need = tdino_off + tdino_bytes;

    if (ws_size >= need) {
        float* Pmat  = (float*)d_ws;
        float* R2    = Pmat + NBV_ * 12;
        float* tdino = (float*)((char*)d_ws + tdino_off);

        dim3 tb(32, 8);
        prep_kernel<<<TP_TOTAL_ + 1, tb, 0, stream>>>(dino, tdino, intr, extr,
                                                      Pmat, R2);
        int gblocks = (N + PTSB_ - 1) / PTSB_;
        gather_fused<<<gblocks, 256, 0, stream>>>(pts, bi, Pmat, R2, tdino,
                                                  out, N);
    } else {
        const int total = N * 96;
        fallback_kernel<<<(total + 255) / 256, 256, 0, stream>>>(
            pts, bi, intr, extr, dino, out, N);
    }
}